// Round 3
// baseline (66.856 us; speedup 1.0000x reference)
//
#include <hip/hip_runtime.h>

#define HID 64
#define NTOK 66          // VOCAB_SIZE + 2
#define SEQ 64
#define WIN0 55          // SEQ_LEN - 1 - MEMORY_SLOTS
#define NW 8
#define LDS_STRIDE 72    // ushorts per table row (144B = 9*16B -> rotates 16B slot across banks)
#define TILES_PER_BLOCK 4
#define ROWS_PER_TILE 64 // 4 waves x 16 rows

typedef short short8 __attribute__((ext_vector_type(8)));
typedef unsigned short ushort8v __attribute__((ext_vector_type(8)));
typedef float float4v __attribute__((ext_vector_type(4)));

static __device__ __forceinline__ unsigned short f2bf(float f) {
    union { float f; unsigned u; } v; v.f = f;
    unsigned r = v.u + 0x7FFFu + ((v.u >> 16) & 1u);
    return (unsigned short)(r >> 16);
}
static __device__ __forceinline__ float bf2f(unsigned short s) {
    union { unsigned u; float f; } v; v.u = ((unsigned)s) << 16;
    return v.f;
}

// Kernel 1: tables T1[t][n] = b1[n] + sum_k emb[t][k]*W1[n][k]
//           T2[t][n] = 0.125 * sum_k emb[t][k]*W1[n][64+k]
// stored bf16 in ws: [2][66][64]
__global__ void build_tables(const float* __restrict__ embed,
                             const float* __restrict__ W1,
                             const float* __restrict__ b1,
                             unsigned short* __restrict__ tbl) {
    int b = blockIdx.x;      // 0..131
    int tb = b & 1;
    int t  = b >> 1;
    int n  = threadIdx.x;    // 0..63
    float acc = tb ? 0.0f : b1[n];
    const float* er = embed + t * HID;
    const float* wr = W1 + n * (2 * HID) + tb * HID;
#pragma unroll 8
    for (int k = 0; k < HID; ++k) acc += er[k] * wr[k];
    if (tb) acc *= 0.125f;
    tbl[tb * (NTOK * HID) + t * HID + n] = f2bf(acc);
}

// Build one chunk (8 consecutive k-values) of h[row] = relu(T1[q] + sum_j T2[w_j])
static __device__ __forceinline__ short8 build_hfrag(
    const unsigned short* T_lds, int q, const int* w, int k0c) {
    ushort8v tv = *(const ushort8v*)(T_lds + q * LDS_STRIDE + k0c);
    float s[8];
#pragma unroll
    for (int d = 0; d < 8; ++d) s[d] = bf2f(tv[d]);
#pragma unroll
    for (int j = 0; j < NW; ++j) {
        ushort8v v2 = *(const ushort8v*)(T_lds + NTOK * LDS_STRIDE + w[j] * LDS_STRIDE + k0c);
#pragma unroll
        for (int d = 0; d < 8; ++d) s[d] += bf2f(v2[d]);
    }
    short8 a;
#pragma unroll
    for (int d = 0; d < 8; ++d) a[d] = (short)f2bf(fmaxf(s[d], 0.0f));
    return a;
}

// Kernel 2: logits^T = W2 (A-op) x h^T (B-op) via mfma_f32_16x16x32_bf16.
// Lane (lrow=l&15, lg=l>>4) owns batch row (tilebase + lrow); D gives it 4
// consecutive floats of its output row -> global_store_dwordx4.
__global__ __launch_bounds__(256, 4) void fused_forward(
    const int* __restrict__ seqs,
    const int* __restrict__ qtok,
    const float* __restrict__ W2,
    const float* __restrict__ b2,
    const unsigned short* __restrict__ tbl,
    float* __restrict__ out)
{
    __shared__ unsigned short T_lds[2 * NTOK * LDS_STRIDE]; // 19008 B

    int tid  = threadIdx.x;
    int wv   = tid >> 6;
    int l    = tid & 63;
    int lrow = l & 15;          // W2 row within n-tile / batch row within tile
    int lg   = l >> 4;
    int lk8  = lg * 8;          // k offset within 32-wide K chunk

    int base_row = blockIdx.x * (TILES_PER_BLOCK * ROWS_PER_TILE) + wv * 16 + lrow;

    // ---- (1) issue ALL token loads first: latency hides under fill+barrier ----
    int q[TILES_PER_BLOCK];
    int w[TILES_PER_BLOCK][NW];
#pragma unroll
    for (int t = 0; t < TILES_PER_BLOCK; ++t) {
        int row = base_row + t * ROWS_PER_TILE;
        q[t] = qtok[row];
        const int* sp = seqs + row * SEQ + WIN0;
#pragma unroll
        for (int j = 0; j < NW; ++j) w[t][j] = sp[j];
    }

    // ---- (2) W2 A-fragments in registers (whole 64x64) + b2 float4 ----
    short8  wfrag[4][2];
    float4v b2v[4];
#pragma unroll
    for (int nt = 0; nt < 4; ++nt) {
        b2v[nt] = *(const float4v*)(b2 + nt * 16 + lg * 4);
#pragma unroll
        for (int kc = 0; kc < 2; ++kc) {
            const float* wp = W2 + (nt * 16 + lrow) * HID + kc * 32 + lk8;
            short8 f;
#pragma unroll
            for (int j = 0; j < 8; ++j) f[j] = (short)f2bf(wp[j]);
            wfrag[nt][kc] = f;
        }
    }

    // ---- (3) fill LDS tables (16B chunks; row stride 144B) ----
    for (int i = tid; i < 2 * NTOK * (HID / 8); i += 256) {
        int tbi = i / (NTOK * 8);
        int rem = i - tbi * (NTOK * 8);
        int t   = rem >> 3;
        int kq  = (rem & 7) << 3;
        *(ushort8v*)(T_lds + tbi * (NTOK * LDS_STRIDE) + t * LDS_STRIDE + kq) =
            *(const ushort8v*)(tbl + tbi * (NTOK * HID) + t * HID + kq);
    }
    __syncthreads();

    // ---- (4) 4 independent tile computes, straight-line; compiler interleaves ----
#pragma unroll
    for (int t = 0; t < TILES_PER_BLOCK; ++t) {
        short8 a0 = build_hfrag(T_lds, q[t], w[t], lk8);
        short8 a1 = build_hfrag(T_lds, q[t], w[t], 32 + lk8);
        float* op = out + (size_t)(base_row + t * ROWS_PER_TILE) * HID;
#pragma unroll
        for (int nt = 0; nt < 4; ++nt) {
            float4v acc = (float4v)(0.0f);
            acc = __builtin_amdgcn_mfma_f32_16x16x32_bf16(wfrag[nt][0], a0, acc, 0, 0, 0);
            acc = __builtin_amdgcn_mfma_f32_16x16x32_bf16(wfrag[nt][1], a1, acc, 0, 0, 0);
            acc += b2v[nt];
            *(float4v*)(op + nt * 16 + lg * 4) = acc;
        }
    }
}

extern "C" void kernel_launch(void* const* d_in, const int* in_sizes, int n_in,
                              void* d_out, int out_size, void* d_ws, size_t ws_size,
                              hipStream_t stream) {
    const int*   seqs  = (const int*)d_in[0];
    const int*   qtok  = (const int*)d_in[1];
    const float* embed = (const float*)d_in[2];
    const float* W1    = (const float*)d_in[3];
    const float* b1    = (const float*)d_in[4];
    const float* W2    = (const float*)d_in[5];
    const float* b2    = (const float*)d_in[6];
    float* out = (float*)d_out;
    unsigned short* tbl = (unsigned short*)d_ws;

    int B = in_sizes[0] / SEQ;

    build_tables<<<NTOK * 2, HID, 0, stream>>>(embed, W1, b1, tbl);

    int grid = B / (TILES_PER_BLOCK * ROWS_PER_TILE);
    fused_forward<<<grid, 256, 0, stream>>>(seqs, qtok, W2, b2, tbl, out);
}

// Round 4
// 59.716 us; speedup vs baseline: 1.1196x; 1.1196x over previous
//
#include <hip/hip_runtime.h>

#define HID 64
#define NTOK 66          // VOCAB_SIZE + 2
#define SEQ 64
#define WIN0 55          // SEQ_LEN - 1 - MEMORY_SLOTS
#define NW 8
#define LDS_STRIDE 72    // ushorts per table row (144B -> row base bank rotates by 4)
#define TILES_PER_BLOCK 4
#define ROWS_PER_TILE 64 // 4 waves x 16 rows

typedef short short8 __attribute__((ext_vector_type(8)));
typedef unsigned short ushort8v __attribute__((ext_vector_type(8)));
typedef unsigned int uint4v __attribute__((ext_vector_type(4)));
typedef float float2v __attribute__((ext_vector_type(2)));
typedef float float4v __attribute__((ext_vector_type(4)));

static __device__ __forceinline__ unsigned short f2bf(float f) {
    union { float f; unsigned u; } v; v.f = f;
    unsigned r = v.u + 0x7FFFu + ((v.u >> 16) & 1u);
    return (unsigned short)(r >> 16);
}
static __device__ __forceinline__ float u2f(unsigned u) {
    union { unsigned u; float f; } v; v.u = u;
    return v.f;
}

// Kernel 1: tables T1[t][n] = b1[n] + sum_k emb[t][k]*W1[n][k]
//           T2[t][n] = 0.125 * sum_k emb[t][k]*W1[n][64+k]
// stored bf16 in ws: [2][66][64]
__global__ void build_tables(const float* __restrict__ embed,
                             const float* __restrict__ W1,
                             const float* __restrict__ b1,
                             unsigned short* __restrict__ tbl) {
    int b = blockIdx.x;      // 0..131
    int tb = b & 1;
    int t  = b >> 1;
    int n  = threadIdx.x;    // 0..63
    float acc = tb ? 0.0f : b1[n];
    const float* er = embed + t * HID;
    const float* wr = W1 + n * (2 * HID) + tb * HID;
#pragma unroll 8
    for (int k = 0; k < HID; ++k) acc += er[k] * wr[k];
    if (tb) acc *= 0.125f;
    tbl[tb * (NTOK * HID) + t * HID + n] = f2bf(acc);
}

// Build one chunk (8 consecutive k) of h[row] = relu(T1[q] + sum_j T2[w_j]).
// bf16-pair dwords unpacked to float2 {lo<<16, hi&0xFFFF0000}; float2 adds
// pair into v_pk_add_f32. First row (T1) initializes the accumulators.
static __device__ __forceinline__ short8 build_hfrag(
    const unsigned short* T_lds, int q, const int* w, int k0c) {
    uint4v tv = *(const uint4v*)(T_lds + q * LDS_STRIDE + k0c);
    float2v acc[4];
#pragma unroll
    for (int i = 0; i < 4; ++i) {
        acc[i].x = u2f(tv[i] << 16);
        acc[i].y = u2f(tv[i] & 0xFFFF0000u);
    }
#pragma unroll
    for (int j = 0; j < NW; ++j) {
        uint4v v2 = *(const uint4v*)(T_lds + NTOK * LDS_STRIDE + w[j] * LDS_STRIDE + k0c);
#pragma unroll
        for (int i = 0; i < 4; ++i) {
            float2v p;
            p.x = u2f(v2[i] << 16);
            p.y = u2f(v2[i] & 0xFFFF0000u);
            acc[i] += p;
        }
    }
    short8 a;
#pragma unroll
    for (int i = 0; i < 4; ++i) {
        a[2 * i]     = (short)f2bf(fmaxf(acc[i].x, 0.0f));
        a[2 * i + 1] = (short)f2bf(fmaxf(acc[i].y, 0.0f));
    }
    return a;
}

// Kernel 2: logits^T = W2 (A-op) x h^T (B-op) via mfma_f32_16x16x32_bf16.
// Lane (lrow=l&15, lg=l>>4) owns batch row (tilebase + lrow); D gives it 4
// consecutive floats of its output row -> global_store_dwordx4.
__global__ __launch_bounds__(256, 4) void fused_forward(
    const int* __restrict__ seqs,
    const int* __restrict__ qtok,
    const float* __restrict__ W2,
    const float* __restrict__ b2,
    const unsigned short* __restrict__ tbl,
    float* __restrict__ out)
{
    __shared__ unsigned short T_lds[2 * NTOK * LDS_STRIDE]; // 19008 B

    int tid  = threadIdx.x;
    int wv   = tid >> 6;
    int l    = tid & 63;
    int lrow = l & 15;          // W2 row within n-tile / batch row within tile
    int lg   = l >> 4;
    int lk8  = lg * 8;          // k offset within 32-wide K chunk

    int base_row = blockIdx.x * (TILES_PER_BLOCK * ROWS_PER_TILE) + wv * 16 + lrow;

    // Token load: q scalar; window ints 55..62 live in the row's last 64B
    // line -> 3x int4 from 16B-aligned int offset 48 (ints 52..63).
#define LOADT(s, t_) { \
    int row_ = base_row + (t_) * ROWS_PER_TILE; \
    q##s = qtok[row_]; \
    const int4* lp_ = (const int4*)(seqs + row_ * SEQ + 48); \
    int4 va_ = lp_[1];  /* ints 52..55 */ \
    int4 vb_ = lp_[2];  /* ints 56..59 */ \
    int4 vc_ = lp_[3];  /* ints 60..63 */ \
    w##s[0] = va_.w; \
    w##s[1] = vb_.x; w##s[2] = vb_.y; w##s[3] = vb_.z; w##s[4] = vb_.w; \
    w##s[5] = vc_.x; w##s[6] = vc_.y; w##s[7] = vc_.z; \
}

#define COMPUTE(s, t_) { \
    short8 a0 = build_hfrag(T_lds, q##s, w##s, lk8); \
    short8 a1 = build_hfrag(T_lds, q##s, w##s, 32 + lk8); \
    float* op = out + (size_t)(base_row + (t_) * ROWS_PER_TILE) * HID; \
    _Pragma("unroll") \
    for (int nt = 0; nt < 4; ++nt) { \
        float4v acc = (float4v)(0.0f); \
        acc = __builtin_amdgcn_mfma_f32_16x16x32_bf16(wfrag[nt][0], a0, acc, 0, 0, 0); \
        acc = __builtin_amdgcn_mfma_f32_16x16x32_bf16(wfrag[nt][1], a1, acc, 0, 0, 0); \
        acc += b2v[nt]; \
        *(float4v*)(op + nt * 16 + lg * 4) = acc; \
    } \
}

    int qA, qB;
    int wA[NW], wB[NW];

    // ---- (1) tiles 0/1 token loads: HBM latency hides under fill+barrier ----
    LOADT(A, 0);
    LOADT(B, 1);

    // ---- (2) W2 A-fragments in registers (whole 64x64) + b2 float4 ----
    short8  wfrag[4][2];
    float4v b2v[4];
#pragma unroll
    for (int nt = 0; nt < 4; ++nt) {
        b2v[nt] = *(const float4v*)(b2 + nt * 16 + lg * 4);
#pragma unroll
        for (int kc = 0; kc < 2; ++kc) {
            const float* wp = W2 + (nt * 16 + lrow) * HID + kc * 32 + lk8;
            short8 f;
#pragma unroll
            for (int j = 0; j < 8; ++j) f[j] = (short)f2bf(wp[j]);
            wfrag[nt][kc] = f;
        }
    }

    // ---- (3) fill LDS tables (16B chunks; row stride 144B) ----
    for (int i = tid; i < 2 * NTOK * (HID / 8); i += 256) {
        int tbi = i / (NTOK * 8);
        int rem = i - tbi * (NTOK * 8);
        int t   = rem >> 3;
        int kq  = (rem & 7) << 3;
        *(ushort8v*)(T_lds + tbi * (NTOK * LDS_STRIDE) + t * LDS_STRIDE + kq) =
            *(const ushort8v*)(tbl + tbi * (NTOK * HID) + t * HID + kq);
    }
    __syncthreads();

    // ---- (4) depth-2 software pipeline over 4 tiles (all indices static) ----
    COMPUTE(A, 0);
    LOADT(A, 2);
    COMPUTE(B, 1);
    LOADT(B, 3);
    COMPUTE(A, 2);
    COMPUTE(B, 3);

#undef LOADT
#undef COMPUTE
}

extern "C" void kernel_launch(void* const* d_in, const int* in_sizes, int n_in,
                              void* d_out, int out_size, void* d_ws, size_t ws_size,
                              hipStream_t stream) {
    const int*   seqs  = (const int*)d_in[0];
    const int*   qtok  = (const int*)d_in[1];
    const float* embed = (const float*)d_in[2];
    const float* W1    = (const float*)d_in[3];
    const float* b1    = (const float*)d_in[4];
    const float* W2    = (const float*)d_in[5];
    const float* b2    = (const float*)d_in[6];
    float* out = (float*)d_out;
    unsigned short* tbl = (unsigned short*)d_ws;

    int B = in_sizes[0] / SEQ;

    build_tables<<<NTOK * 2, HID, 0, stream>>>(embed, W1, b1, tbl);

    int grid = B / (TILES_PER_BLOCK * ROWS_PER_TILE);
    fused_forward<<<grid, 256, 0, stream>>>(seqs, qtok, W2, b2, tbl, out);
}

// Round 5
// 54.688 us; speedup vs baseline: 1.2225x; 1.0920x over previous
//
#include <hip/hip_runtime.h>

#define HID 64
#define NTOK 66          // VOCAB_SIZE + 2
#define SEQ 64
#define WIN0 55          // SEQ_LEN - 1 - MEMORY_SLOTS
#define NW 8
#define LDS_STRIDE 72    // ushorts per table row (144B -> row base bank rotates by 4)
#define ITERS 8          // iterations per block (rows/block = 512)
#define ROWS_PER_ITER 64 // 4 waves x 16 rows

typedef short short8 __attribute__((ext_vector_type(8)));
typedef unsigned short ushort8v __attribute__((ext_vector_type(8)));
typedef unsigned int uint4v __attribute__((ext_vector_type(4)));
typedef float float2v __attribute__((ext_vector_type(2)));
typedef float float4v __attribute__((ext_vector_type(4)));

static __device__ __forceinline__ unsigned short f2bf(float f) {
    union { float f; unsigned u; } v; v.f = f;
    unsigned r = v.u + 0x7FFFu + ((v.u >> 16) & 1u);
    return (unsigned short)(r >> 16);
}
static __device__ __forceinline__ float u2f(unsigned u) {
    union { unsigned u; float f; } v; v.u = u;
    return v.f;
}

// Kernel 1: tables T1[t][n] = b1[n] + sum_k emb[t][k]*W1[n][k]
//           T2[t][n] = 0.125 * sum_k emb[t][k]*W1[n][64+k]
// stored bf16 in ws: [2][66][64]
__global__ void build_tables(const float* __restrict__ embed,
                             const float* __restrict__ W1,
                             const float* __restrict__ b1,
                             unsigned short* __restrict__ tbl) {
    int b = blockIdx.x;      // 0..131
    int tb = b & 1;
    int t  = b >> 1;
    int n  = threadIdx.x;    // 0..63
    float acc = tb ? 0.0f : b1[n];
    const float* er = embed + t * HID;
    const float* wr = W1 + n * (2 * HID) + tb * HID;
#pragma unroll 8
    for (int k = 0; k < HID; ++k) acc += er[k] * wr[k];
    if (tb) acc *= 0.125f;
    tbl[tb * (NTOK * HID) + t * HID + n] = f2bf(acc);
}

// Build one chunk (8 consecutive k) of h[row] = relu(T1[q] + sum_j T2[w_j]).
// bf16-pair dwords unpacked to float2 {lo<<16, hi&0xFFFF0000}; float2 adds
// pair into v_pk_add_f32. T1 row initializes the accumulators.
static __device__ __forceinline__ short8 build_hfrag(
    const unsigned short* T_lds, int q, const int* w, int k0c) {
    uint4v tv = *(const uint4v*)(T_lds + q * LDS_STRIDE + k0c);
    float2v acc[4];
#pragma unroll
    for (int i = 0; i < 4; ++i) {
        acc[i].x = u2f(tv[i] << 16);
        acc[i].y = u2f(tv[i] & 0xFFFF0000u);
    }
#pragma unroll
    for (int j = 0; j < NW; ++j) {
        uint4v v2 = *(const uint4v*)(T_lds + NTOK * LDS_STRIDE + w[j] * LDS_STRIDE + k0c);
#pragma unroll
        for (int i = 0; i < 4; ++i) {
            float2v p;
            p.x = u2f(v2[i] << 16);
            p.y = u2f(v2[i] & 0xFFFF0000u);
            acc[i] += p;
        }
    }
    short8 a;
#pragma unroll
    for (int i = 0; i < 4; ++i) {
        a[2 * i]     = (short)f2bf(fmaxf(acc[i].x, 0.0f));
        a[2 * i + 1] = (short)f2bf(fmaxf(acc[i].y, 0.0f));
    }
    return a;
}

// Kernel 2: logits^T = W2 (A-op) x h^T (B-op) via mfma_f32_16x16x32_bf16.
// Persistent-ish: grid = B/512; each block does 8 unrolled iterations of
// 64 rows (4 waves x 16), depth-2 A/B token pipeline, one barrier total.
__global__ __launch_bounds__(256, 4) void fused_forward(
    const int* __restrict__ seqs,
    const int* __restrict__ qtok,
    const float* __restrict__ W2,
    const float* __restrict__ b2,
    const unsigned short* __restrict__ tbl,
    float* __restrict__ out)
{
    __shared__ unsigned short T_lds[2 * NTOK * LDS_STRIDE]; // 19008 B

    int tid  = threadIdx.x;
    int wv   = tid >> 6;
    int l    = tid & 63;
    int lrow = l & 15;          // W2 row within n-tile / batch row within tile
    int lg   = l >> 4;
    int lk8  = lg * 8;          // k offset within 32-wide K chunk

    // this lane's batch row at iteration 0; iteration t adds t*64
    int row0 = blockIdx.x * (ITERS * ROWS_PER_ITER) + wv * 16 + lrow;

    // scalar token loads (round-2 form: cleanest HBM traffic)
#define LOADT(s, t_) { \
    int row_ = row0 + (t_) * ROWS_PER_ITER; \
    q##s = qtok[row_]; \
    const int* sp_ = seqs + row_ * SEQ + WIN0; \
    _Pragma("unroll") \
    for (int j = 0; j < NW; ++j) w##s[j] = sp_[j]; \
}

#define COMPUTE(s, t_) { \
    short8 a0 = build_hfrag(T_lds, q##s, w##s, lk8); \
    short8 a1 = build_hfrag(T_lds, q##s, w##s, 32 + lk8); \
    float* op = out + (size_t)(row0 + (t_) * ROWS_PER_ITER) * HID; \
    _Pragma("unroll") \
    for (int nt = 0; nt < 4; ++nt) { \
        float4v acc = (float4v)(0.0f); \
        acc = __builtin_amdgcn_mfma_f32_16x16x32_bf16(wfrag[nt][0], a0, acc, 0, 0, 0); \
        acc = __builtin_amdgcn_mfma_f32_16x16x32_bf16(wfrag[nt][1], a1, acc, 0, 0, 0); \
        acc += b2v[nt]; \
        *(float4v*)(op + nt * 16 + lg * 4) = acc; \
    } \
}

    int qA, qB;
    int wA[NW], wB[NW];

    // ---- (1) iter 0/1 token loads: HBM latency hides under W2+fill+barrier ----
    LOADT(A, 0);
    LOADT(B, 1);

    // ---- (2) W2 A-fragments in registers (whole 64x64) + b2 float4 ----
    short8  wfrag[4][2];
    float4v b2v[4];
#pragma unroll
    for (int nt = 0; nt < 4; ++nt) {
        b2v[nt] = *(const float4v*)(b2 + nt * 16 + lg * 4);
#pragma unroll
        for (int kc = 0; kc < 2; ++kc) {
            const float* wp = W2 + (nt * 16 + lrow) * HID + kc * 32 + lk8;
            short8 f;
#pragma unroll
            for (int j = 0; j < 8; ++j) f[j] = (short)f2bf(wp[j]);
            wfrag[nt][kc] = f;
        }
    }

    // ---- (3) fill LDS tables (16B chunks; row stride 144B) ----
    for (int i = tid; i < 2 * NTOK * (HID / 8); i += 256) {
        int tbi = i / (NTOK * 8);
        int rem = i - tbi * (NTOK * 8);
        int t   = rem >> 3;
        int kq  = (rem & 7) << 3;
        *(ushort8v*)(T_lds + tbi * (NTOK * LDS_STRIDE) + t * LDS_STRIDE + kq) =
            *(const ushort8v*)(tbl + tbi * (NTOK * HID) + t * HID + kq);
    }
    __syncthreads();

    // ---- (4) 8 iterations, straight-line depth-2 pipeline (all static) ----
    COMPUTE(A, 0); LOADT(A, 2);
    COMPUTE(B, 1); LOADT(B, 3);
    COMPUTE(A, 2); LOADT(A, 4);
    COMPUTE(B, 3); LOADT(B, 5);
    COMPUTE(A, 4); LOADT(A, 6);
    COMPUTE(B, 5); LOADT(B, 7);
    COMPUTE(A, 6);
    COMPUTE(B, 7);

#undef LOADT
#undef COMPUTE
}

extern "C" void kernel_launch(void* const* d_in, const int* in_sizes, int n_in,
                              void* d_out, int out_size, void* d_ws, size_t ws_size,
                              hipStream_t stream) {
    const int*   seqs  = (const int*)d_in[0];
    const int*   qtok  = (const int*)d_in[1];
    const float* embed = (const float*)d_in[2];
    const float* W1    = (const float*)d_in[3];
    const float* b1    = (const float*)d_in[4];
    const float* W2    = (const float*)d_in[5];
    const float* b2    = (const float*)d_in[6];
    float* out = (float*)d_out;
    unsigned short* tbl = (unsigned short*)d_ws;

    int B = in_sizes[0] / SEQ;

    build_tables<<<NTOK * 2, HID, 0, stream>>>(embed, W1, b1, tbl);

    int grid = B / (ITERS * ROWS_PER_ITER);
    fused_forward<<<grid, 256, 0, stream>>>(seqs, qtok, W2, b2, tbl, out);
}